// Round 11
// baseline (123.472 us; speedup 1.0000x reference)
//
#include <hip/hip_runtime.h>
#include <math.h>

#define NEG_INF (-INFINITY)

__device__ __forceinline__ float nll3(float l0, float l1, float l2) {
    float m = fmaxf(l0, fmaxf(l1, l2));
    float e0 = __expf(l0 - m);
    float e1 = __expf(l1 - m);
    float e2 = __expf(l2 - m);
    return __logf(e0 + e1 + e2) - (l0 - m);
}

// problem sizes
#define S0 262144          // 64^3
#define S1 32768           // 32^3
#define N0 (12 * S0)       // 3,145,728
#define N1 (12 * S1)       //   393,216
#define N0_4 (N0 / 4)      // 786,432
#define N1_4 (N1 / 4)      //  98,304
#define P1_NLL_BLOCKS ((N0_4 + N1_4) / 256)   // 3456
#define P1_BLOCKS (P1_NLL_BLOCKS + 4)         // + 16 pos waves

// pass-2 geometry
#define NW0 3072           // L0: NR=2, TD=8 -> 12*32*8
#define NW1 384            // L1: NR=4, TD=8 -> 12*8*4
#define P2_BLOCKS ((NW0 + NW1) / 4)           // 864
// slot layout in ws after the nll map: [864 neg block slots][16 pos slots][counter]
#define NSLOT_NEG P2_BLOCKS
#define NSLOT (NSLOT_NEG + 16)

// ---------------------------------------------------------------------------
// Pass 1: streaming nll compute (one float4/thread, fully coalesced), plus
// 16 trailing pos-gather waves, plus counter reset (block 0).
// ---------------------------------------------------------------------------
__device__ void pos_wave(int level, int sub, int lane,
                         const float* __restrict__ logit,
                         const float* __restrict__ prob_gt,
                         const int* __restrict__ coord,
                         const float* __restrict__ wcls,
                         float2* __restrict__ slot,
                         int D, int H, int W) {
    const int A = 3, P = 128;
    const long S = (long)D * H * W;
    const int i = sub * 64 + lane;          // < 512
    const int b = i / P;
    const int* c = coord + (long)i * 4;
    const int a = c[0];
    float loss = 0.f, cnt = 0.f;
    if (a > -1) {
        const int d = c[1], h = c[2], w = c[3];
        const long s = ((long)d * H + h) * W + w;
        const int cls = (int)prob_gt[((long)b * A + a) * S + s];
        const float* lp = logit + ((long)b * 3 * A + a) * S + s;
        float l0 = lp[0];
        float l1 = lp[(long)A * S];
        float l2 = lp[2L * A * S];
        float m = fmaxf(l0, fmaxf(l1, l2));
        float e0 = __expf(l0 - m);
        float e1 = __expf(l1 - m);
        float e2 = __expf(l2 - m);
        float lsum = __logf(e0 + e1 + e2);
        float lc = (cls == 0) ? l0 : ((cls == 1) ? l1 : l2);
        float lpc = (lc - m) - lsum;
        float pt = __expf(lpc);
        float wp = (1.f - pt) * (1.f - pt) * wcls[cls];
        loss = (-lpc) * wp;
        cnt = wp;
    }
#pragma unroll
    for (int off = 32; off > 0; off >>= 1) {
        loss += __shfl_down(loss, off);
        cnt  += __shfl_down(cnt, off);
    }
    if (lane == 0) *slot = make_float2(loss, cnt);
}

__global__ __launch_bounds__(256)
void nll_pos_pass(const float* __restrict__ logit0,
                  const float* __restrict__ logit1,
                  const float* __restrict__ pg0,
                  const float* __restrict__ pg1,
                  const int* __restrict__ coord0,
                  const int* __restrict__ coord1,
                  const float* __restrict__ wcls,
                  float* __restrict__ nllws,
                  float2* __restrict__ slots,
                  unsigned int* __restrict__ counter) {
    if (blockIdx.x == 0 && threadIdx.x == 0) *counter = 0u;  // reset for pass 2
    if (blockIdx.x < P1_NLL_BLOCKS) {
        const int idx = blockIdx.x * 256 + threadIdx.x;
        if (idx < N0_4) {
            const int per = S0 / 4;
            const int ba = idx / per, r4 = idx % per;
            const int a = ba % 3, b = ba / 3;
            const float* p = logit0 + ((long)b * 9 + a) * S0 + (long)r4 * 4;
            float4 l0 = *(const float4*)p;
            float4 l1 = *(const float4*)(p + (long)3 * S0);
            float4 l2 = *(const float4*)(p + (long)6 * S0);
            float4 o;
            o.x = nll3(l0.x, l1.x, l2.x);
            o.y = nll3(l0.y, l1.y, l2.y);
            o.z = nll3(l0.z, l1.z, l2.z);
            o.w = nll3(l0.w, l1.w, l2.w);
            *(float4*)(nllws + (long)ba * S0 + (long)r4 * 4) = o;
        } else {
            const int j = idx - N0_4;
            const int per = S1 / 4;
            const int ba = j / per, r4 = j % per;
            const int a = ba % 3, b = ba / 3;
            const float* p = logit1 + ((long)b * 9 + a) * S1 + (long)r4 * 4;
            float4 l0 = *(const float4*)p;
            float4 l1 = *(const float4*)(p + (long)3 * S1);
            float4 l2 = *(const float4*)(p + (long)6 * S1);
            float4 o;
            o.x = nll3(l0.x, l1.x, l2.x);
            o.y = nll3(l0.y, l1.y, l2.y);
            o.z = nll3(l0.z, l1.z, l2.z);
            o.w = nll3(l0.w, l1.w, l2.w);
            *(float4*)(nllws + N0 + (long)ba * S1 + (long)r4 * 4) = o;
        }
    } else {
        const int gp = (blockIdx.x - P1_NLL_BLOCKS) * 4 + (threadIdx.x >> 6);
        const int lane = threadIdx.x & 63;
        if (gp < 8)
            pos_wave(0, gp, lane, logit0, pg0, coord0, wcls,
                     slots + NSLOT_NEG + gp, 64, 64, 64);
        else
            pos_wave(1, gp - 8, lane, logit1, pg1, coord1, wcls,
                     slots + NSLOT_NEG + gp, 32, 32, 32);
    }
}

// ---------------------------------------------------------------------------
// Pass 2: NMS + focal weighting from the precomputed nll map.
// Wave-strip layout (LR = W/4 lanes/row, group g = input row h0-1+g).
// Mod-3 register pipeline without copies (verified bit-exact in R10).
// Returns per-wave partials; block reduces via LDS; last block folds all
// slots and writes out[0..3] (threadFenceReduction pattern).
// ---------------------------------------------------------------------------
template<int W, int NR, int TD, int D, int H>
__device__ void nms_strip(int uid, int lane,
                          const float* __restrict__ nlvl,
                          const float* __restrict__ pg,
                          float& loss_out, float& cnt_out) {
    constexpr int LR = W / 4;
    constexpr int NI = NR + 2;
    constexpr int HG = H / NR;
    constexpr int DT = D / TD;
    const int q = lane % LR;
    const int g = lane / LR;

    int t = uid;
    const int hg = t % HG; t /= HG;
    const int dt = t % DT; t /= DT;
    const int ba = t;                   // b*3 + a
    const int h0 = hg * NR, d0 = dt * TD;
    const int HW = H * W;
    const long S = (long)D * HW;
    const float* nb  = nlvl + (long)ba * S;
    const float* pgb = pg + (long)ba * S;

    const int jrow = h0 - 1 + g;
    const bool hv = (jrow >= 0) && (jrow < H) && (g < NI);
    const int hcl = min(max(jrow, 0), H - 1);
    const int rowoff = hcl * W + 4 * q;
    const int prowoff = (h0 + min(g, NR - 1)) * W + 4 * q;

    float4 nl[3]; bool vd[3]; float4 pq[3];
    nl[0] = *(const float4*)(nb + (long)max(d0 - 1, 0) * HW + rowoff);
    vd[0] = (d0 - 1 >= 0);
    nl[1] = *(const float4*)(nb + (long)d0 * HW + rowoff);
    vd[1] = true;
    nl[2] = make_float4(0.f, 0.f, 0.f, 0.f); vd[2] = false;
    pq[0] = pq[1] = pq[2] = make_float4(0.f, 0.f, 0.f, 0.f);

    float vm0[4], vm1[4], cc1[4];
#pragma unroll
    for (int i = 0; i < 4; ++i) { vm0[i] = NEG_INF; vm1[i] = NEG_INF; cc1[i] = 0.f; }

    float loss = 0.f, cnt = 0.f;

#pragma unroll
    for (int s = 0; s <= TD + 1; ++s) {
        if (s <= TD - 1) {                                // static guard
            const int pd = d0 + 1 + s;
            nl[(s + 2) % 3] = *(const float4*)(nb + (long)min(pd, D - 1) * HW + rowoff);
            vd[(s + 2) % 3] = (pd < D);
            pq[s % 3] = *(const float4*)(pgb + (long)(d0 + s) * HW + prowoff);
        }

        const float4 cv = nl[s % 3];
        const bool vv = vd[s % 3] && hv;
        float nvv[4];
        nvv[0] = vv ? cv.x : NEG_INF;
        nvv[1] = vv ? cv.y : NEG_INF;
        nvv[2] = vv ? cv.z : NEG_INF;
        nvv[3] = vv ? cv.w : NEG_INF;

        float le = __shfl(nvv[3], lane - 1);
        float re = __shfl(nvv[0], lane + 1);
        le = (q == 0)      ? NEG_INF : le;
        re = (q == LR - 1) ? NEG_INF : re;
        float rm[4];
        rm[0] = fmaxf(le,     fmaxf(nvv[0], nvv[1]));
        rm[1] = fmaxf(nvv[0], fmaxf(nvv[1], nvv[2]));
        rm[2] = fmaxf(nvv[1], fmaxf(nvv[2], nvv[3]));
        rm[3] = fmaxf(nvv[2], fmaxf(nvv[3], re));

        float rmA[4], rmB[4], ctr[4];
#pragma unroll
        for (int i = 0; i < 4; ++i) {
            rmA[i] = __shfl(rm[i],  lane + LR);
            rmB[i] = __shfl(rm[i],  lane + 2 * LR);
            ctr[i] = __shfl(nvv[i], lane + LR);
        }

        const float4 gpv = pq[(s + 1) % 3];   // == (s-2)%3 for s>=2
        const float pgv[4] = {gpv.x, gpv.y, gpv.z, gpv.w};
#pragma unroll
        for (int i = 0; i < 4; ++i) {
            float hw2 = fmaxf(rm[i], fmaxf(rmA[i], rmB[i]));
            if (s >= 2 && g < NR && pgv[i] == -1.0f) {
                float mp = fmaxf(vm0[i], fmaxf(vm1[i], hw2));
                if (mp == cc1[i]) {
                    float pn = __expf(-cc1[i]);
                    float wn = (1.f - pn) * (1.f - pn);
                    loss += cc1[i] * wn;
                    cnt  += wn;
                }
            }
            vm0[i] = vm1[i]; vm1[i] = hw2; cc1[i] = ctr[i];
        }
    }

#pragma unroll
    for (int off = 32; off > 0; off >>= 1) {
        loss += __shfl_down(loss, off);
        cnt  += __shfl_down(cnt, off);
    }
    loss_out = loss; cnt_out = cnt;
}

__global__ __launch_bounds__(256)
void nms_pass(const float* __restrict__ nllws,
              const float* __restrict__ pg0,
              const float* __restrict__ pg1,
              float2* __restrict__ slots,
              unsigned int* __restrict__ counter,
              float* __restrict__ out) {
    const int gw = blockIdx.x * 4 + (threadIdx.x >> 6);
    const int lane = threadIdx.x & 63;
    float loss, cnt;
    if (gw < NW0) {
        nms_strip<64, 2, 8, 64, 64>(gw, lane, nllws, pg0, loss, cnt);
    } else {
        nms_strip<32, 4, 8, 32, 32>(gw - NW0, lane, nllws + N0, pg1, loss, cnt);
    }

    // block-level reduce -> one slot per block
    __shared__ float sl[4], sc[4];
    __shared__ int amLast;
    const int wv = threadIdx.x >> 6;
    if (lane == 0) { sl[wv] = loss; sc[wv] = cnt; }
    __syncthreads();
    if (threadIdx.x == 0) {
        float L = sl[0] + sl[1] + sl[2] + sl[3];
        float C = sc[0] + sc[1] + sc[2] + sc[3];
        slots[blockIdx.x] = make_float2(L, C);
        __threadfence();                      // make slot visible device-wide
        unsigned prev = atomicAdd(counter, 1u);
        amLast = (prev == P2_BLOCKS - 1);
    }
    __syncthreads();

    if (amLast) {
        __threadfence();                      // acquire all blocks' slots
        float ln = 0.f, cn = 0.f, lp = 0.f, cp = 0.f;
        for (int i = threadIdx.x; i < NSLOT_NEG; i += 256) {
            float2 v = slots[i]; ln += v.x; cn += v.y;
        }
        if (threadIdx.x < 16) {
            float2 v = slots[NSLOT_NEG + threadIdx.x]; lp = v.x; cp = v.y;
        }
#pragma unroll
        for (int off = 32; off > 0; off >>= 1) {
            ln += __shfl_down(ln, off); cn += __shfl_down(cn, off);
            lp += __shfl_down(lp, off); cp += __shfl_down(cp, off);
        }
        __shared__ float fr[4][4];
        if (lane == 0) {
            fr[wv][0] = ln; fr[wv][1] = cn; fr[wv][2] = lp; fr[wv][3] = cp;
        }
        __syncthreads();
        if (threadIdx.x == 0) {
            float a = 0.f, b = 0.f, c = 0.f, d = 0.f;
#pragma unroll
            for (int i = 0; i < 4; ++i) {
                a += fr[i][0]; b += fr[i][1]; c += fr[i][2]; d += fr[i][3];
            }
            out[0] = c;   // loss_pos
            out[1] = a;   // loss_neg
            out[2] = d;   // count_pos
            out[3] = b;   // count_neg
        }
    }
}

extern "C" void kernel_launch(void* const* d_in, const int* in_sizes, int n_in,
                              void* d_out, int out_size, void* d_ws, size_t ws_size,
                              hipStream_t stream) {
    const float* logit0   = (const float*)d_in[0];
    const float* logit1   = (const float*)d_in[1];
    const float* prob_gt0 = (const float*)d_in[2];
    const float* prob_gt1 = (const float*)d_in[3];
    const int*   coord0   = (const int*)d_in[4];
    const int*   coord1   = (const int*)d_in[5];
    const float* wcls     = (const float*)d_in[6];
    float* out = (float*)d_out;

    float*        nllws   = (float*)d_ws;                     // N0+N1 floats
    float2*       slots   = (float2*)(nllws + N0 + N1);       // NSLOT float2
    unsigned int* counter = (unsigned int*)(slots + NSLOT);   // 1 uint

    nll_pos_pass<<<P1_BLOCKS, 256, 0, stream>>>(
        logit0, logit1, prob_gt0, prob_gt1, coord0, coord1, wcls,
        nllws, slots, counter);
    nms_pass<<<P2_BLOCKS, 256, 0, stream>>>(
        nllws, prob_gt0, prob_gt1, slots, counter, out);
}

// Round 12
// 106.183 us; speedup vs baseline: 1.1628x; 1.1628x over previous
//
#include <hip/hip_runtime.h>
#include <math.h>

#define NEG_INF (-INFINITY)

__device__ __forceinline__ float nll3(float l0, float l1, float l2) {
    float m = fmaxf(l0, fmaxf(l1, l2));
    float e0 = __expf(l0 - m);
    float e1 = __expf(l1 - m);
    float e2 = __expf(l2 - m);
    return __logf(e0 + e1 + e2) - (l0 - m);
}

// ---------------------------------------------------------------------------
// Depth-2-pipelined, vectorized, barrier/atomic-free neg-loss strip.
// Best-measured variant of the session (105.91 us total).
// Wave layout: LR = W/4 lanes per row; lane group g holds input row h0-1+g
// as a float4. Groups 0..NR-1 emit output rows h0..h0+NR-1. Register
// plane-sets A (consume), B (+1), C (+2): step s consumes loads issued at
// step s-2. All loads unconditional (clamped addr, -inf select after).
// ---------------------------------------------------------------------------
template<int W, int NR, int TD, int D, int H>
__device__ void neg_strip_p2(int uid, int lane,
                             const float* __restrict__ logit,
                             const float* __restrict__ pg,
                             float2* __restrict__ slot) {
    constexpr int LR = W / 4;
    constexpr int NI = NR + 2;
    constexpr int HG = H / NR;
    constexpr int DT = D / TD;
    const int q = lane % LR;
    const int g = lane / LR;

    int t = uid;
    const int hg = t % HG; t /= HG;
    const int dt = t % DT; t /= DT;
    const int ba = t;                  // b*3 + a (A == 3)
    const int a = ba % 3, b = ba / 3;
    const int h0 = hg * NR, d0 = dt * TD;
    const int HW = H * W;

    const long S = (long)D * HW;
    const float* lb  = logit + ((long)b * 9 + a) * S;   // class-0 plane
    const long  cs   = 3 * S;                           // A*S
    const float* pgb = pg + (long)ba * S;

    const int jrow = h0 - 1 + g;
    const bool hv = (jrow >= 0) && (jrow < H) && (g < NI);
    const int hcl = min(max(jrow, 0), H - 1);
    const int rowoff = hcl * W + 4 * q;
    const int prowoff = (h0 + min(g, NR - 1)) * W + 4 * q;

    float4 A0, A1, A2, B0, B1, B2, C0, C1, C2;
    float4 GA, GB, GC;
    bool vA, vB, vC;

    {   // prologue: planes d0-1 and d0
        const float* p = lb + (long)max(d0 - 1, 0) * HW + rowoff;
        A0 = *(const float4*)p;
        A1 = *(const float4*)(p + cs);
        A2 = *(const float4*)(p + 2 * cs);
        vA = (d0 - 1 >= 0);
        const float* p2 = lb + (long)d0 * HW + rowoff;
        B0 = *(const float4*)p2;
        B1 = *(const float4*)(p2 + cs);
        B2 = *(const float4*)(p2 + 2 * cs);
        vB = true;
        GA = make_float4(0.f, 0.f, 0.f, 0.f);
        GB = make_float4(0.f, 0.f, 0.f, 0.f);
    }

    float vm0[4], vm1[4], cc1[4];
#pragma unroll
    for (int i = 0; i < 4; ++i) { vm0[i] = NEG_INF; vm1[i] = NEG_INF; cc1[i] = 0.f; }

    float loss = 0.f, cnt = 0.f;

#pragma unroll
    for (int s = 0; s <= TD + 1; ++s) {
        // ---- depth-2 prefetch: class plane d0+1+s, pg plane d0+s ----
        if (s <= TD - 1) {                              // compile-time guard
            const int pd = d0 + 1 + s;
            const float* p = lb + (long)min(pd, D - 1) * HW + rowoff;
            C0 = *(const float4*)p;
            C1 = *(const float4*)(p + cs);
            C2 = *(const float4*)(p + 2 * cs);
            vC = (pd < D);
            GC = *(const float4*)(pgb + (long)(d0 + s) * HW + prowoff);
        } else {
            vC = false;
            C0 = C1 = C2 = make_float4(0.f, 0.f, 0.f, 0.f);
            GC = make_float4(0.f, 0.f, 0.f, 0.f);
        }

        // ---- nll of plane d0-1+s (set A) ----
        float nvv[4];
        {
            const bool vv = vA && hv;
            nvv[0] = vv ? nll3(A0.x, A1.x, A2.x) : NEG_INF;
            nvv[1] = vv ? nll3(A0.y, A1.y, A2.y) : NEG_INF;
            nvv[2] = vv ? nll3(A0.z, A1.z, A2.z) : NEG_INF;
            nvv[3] = vv ? nll3(A0.w, A1.w, A2.w) : NEG_INF;
        }

        // ---- in-row 3-wide max ----
        float le = __shfl(nvv[3], lane - 1);
        float re = __shfl(nvv[0], lane + 1);
        le = (q == 0)      ? NEG_INF : le;
        re = (q == LR - 1) ? NEG_INF : re;
        float rm[4];
        rm[0] = fmaxf(le,     fmaxf(nvv[0], nvv[1]));
        rm[1] = fmaxf(nvv[0], fmaxf(nvv[1], nvv[2]));
        rm[2] = fmaxf(nvv[1], fmaxf(nvv[2], nvv[3]));
        rm[3] = fmaxf(nvv[2], fmaxf(nvv[3], re));

        // ---- cross-row: group r gets rows r+1, r+2, center row r+1 ----
        float rmA[4], rmB[4], ctr[4];
#pragma unroll
        for (int i = 0; i < 4; ++i) {
            rmA[i] = __shfl(rm[i],  lane + LR);
            rmB[i] = __shfl(rm[i],  lane + 2 * LR);
            ctr[i] = __shfl(nvv[i], lane + LR);
        }

        // ---- 3-deep d-window + emit (center plane d0+s-2, pg in GA) ----
        const float pgv[4] = {GA.x, GA.y, GA.z, GA.w};
#pragma unroll
        for (int i = 0; i < 4; ++i) {
            float hw2 = fmaxf(rm[i], fmaxf(rmA[i], rmB[i]));
            if (s >= 2 && g < NR && pgv[i] == -1.0f) {
                float mp = fmaxf(vm0[i], fmaxf(vm1[i], hw2));
                if (mp == cc1[i]) {
                    float pn = __expf(-cc1[i]);
                    float wn = (1.f - pn) * (1.f - pn);
                    loss += cc1[i] * wn;
                    cnt  += wn;
                }
            }
            vm0[i] = vm1[i]; vm1[i] = hw2; cc1[i] = ctr[i];
        }

        // ---- rotate pipeline sets ----
        GA = GB; GB = GC;
        A0 = B0; A1 = B1; A2 = B2; vA = vB;
        B0 = C0; B1 = C1; B2 = C2; vB = vC;
    }

#pragma unroll
    for (int off = 32; off > 0; off >>= 1) {
        loss += __shfl_down(loss, off);
        cnt  += __shfl_down(cnt, off);
    }
    if (lane == 0) slot[uid] = make_float2(loss, cnt);
}

// ---------------------------------------------------------------------------
// Positive gathers: 8 waves per level, 1 item per lane (B*P = 512).
// ---------------------------------------------------------------------------
__device__ void pos_wave8(int sub, int lane,
                          const float* __restrict__ logit,
                          const float* __restrict__ prob_gt,
                          const int* __restrict__ coord,
                          const float* __restrict__ wcls,
                          float2* __restrict__ slot,
                          int D, int H, int W) {
    const int A = 3, P = 128;
    const long S = (long)D * H * W;
    const int i = sub * 64 + lane;          // < 512
    const int b = i / P;
    const int* c = coord + (long)i * 4;
    const int a = c[0];
    float loss = 0.f, cnt = 0.f;
    if (a > -1) {
        const int d = c[1], h = c[2], w = c[3];
        const long s = ((long)d * H + h) * W + w;
        const int cls = (int)prob_gt[((long)b * A + a) * S + s];
        const float* lp = logit + ((long)b * 3 * A + a) * S + s;
        float l0 = lp[0];
        float l1 = lp[(long)A * S];
        float l2 = lp[2L * A * S];
        float m = fmaxf(l0, fmaxf(l1, l2));
        float e0 = __expf(l0 - m);
        float e1 = __expf(l1 - m);
        float e2 = __expf(l2 - m);
        float lsum = __logf(e0 + e1 + e2);
        float lc = (cls == 0) ? l0 : ((cls == 1) ? l1 : l2);
        float lpc = (lc - m) - lsum;
        float pt = __expf(lpc);
        float wp = (1.f - pt) * (1.f - pt) * wcls[cls];
        loss = (-lpc) * wp;
        cnt = wp;
    }
#pragma unroll
    for (int off = 32; off > 0; off >>= 1) {
        loss += __shfl_down(loss, off);
        cnt  += __shfl_down(cnt, off);
    }
    if (lane == 0) *slot = make_float2(loss, cnt);
}

// ---------------------------------------------------------------------------
// Work split (wave-indexed, barrier-free):
//   L0: W=64, NR=2, TD=8 -> 12*32*8 = 3072 waves
//   L1: W=32, NR=4, TD=8 -> 12*8*4  =  384 waves
//   pos: 8 + 8 waves                     TOTAL 3472 -> 868 blocks
// ---------------------------------------------------------------------------
#define NW0 3072
#define NW1 384
#define NWP 16
#define NUNEG (NW0 + NW1)
#define TOTAL_WAVES (NW0 + NW1 + NWP)   // 3472 = 868 * 4

__global__ __launch_bounds__(256)
void mega_kernel(const float* __restrict__ logit0,
                 const float* __restrict__ logit1,
                 const float* __restrict__ pg0,
                 const float* __restrict__ pg1,
                 const int* __restrict__ coord0,
                 const int* __restrict__ coord1,
                 const float* __restrict__ wcls,
                 float2* __restrict__ ws) {
    const int gw = blockIdx.x * 4 + (threadIdx.x >> 6);
    const int lane = threadIdx.x & 63;
    float2* wsneg = ws;
    float2* wspos = ws + NUNEG;
    if (gw < NW0) {
        neg_strip_p2<64, 2, 8, 64, 64>(gw, lane, logit0, pg0, wsneg);
    } else if (gw < NW0 + NW1) {
        neg_strip_p2<32, 4, 8, 32, 32>(gw - NW0, lane, logit1, pg1, wsneg + NW0);
    } else if (gw < NW0 + NW1 + 8) {
        const int sub = gw - NW0 - NW1;
        pos_wave8(sub, lane, logit0, pg0, coord0, wcls, wspos + sub, 64, 64, 64);
    } else {
        const int sub = gw - NW0 - NW1 - 8;
        pos_wave8(sub, lane, logit1, pg1, coord1, wcls, wspos + 8 + sub, 32, 32, 32);
    }
}

// ---------------------------------------------------------------------------
// Final reduction: one 1024-thread block sums all slots, writes out[0..3].
// ---------------------------------------------------------------------------
__global__ __launch_bounds__(1024)
void final_reduce(const float2* __restrict__ ws, float* __restrict__ out) {
    const float2* wsneg = ws;
    const float2* wspos = ws + NUNEG;
    float ln = 0.f, cn = 0.f, lp = 0.f, cp = 0.f;
    for (int i = threadIdx.x; i < NUNEG; i += 1024) {
        float2 v = wsneg[i]; ln += v.x; cn += v.y;
    }
    if (threadIdx.x < NWP) {
        float2 v = wspos[threadIdx.x]; lp = v.x; cp = v.y;
    }
#pragma unroll
    for (int off = 32; off > 0; off >>= 1) {
        ln += __shfl_down(ln, off); cn += __shfl_down(cn, off);
        lp += __shfl_down(lp, off); cp += __shfl_down(cp, off);
    }
    __shared__ float s[16][4];
    const int wv = threadIdx.x >> 6;
    if ((threadIdx.x & 63) == 0) {
        s[wv][0] = ln; s[wv][1] = cn; s[wv][2] = lp; s[wv][3] = cp;
    }
    __syncthreads();
    if (threadIdx.x == 0) {
        float a = 0.f, b = 0.f, c = 0.f, d = 0.f;
#pragma unroll
        for (int i = 0; i < 16; ++i) {
            a += s[i][0]; b += s[i][1]; c += s[i][2]; d += s[i][3];
        }
        out[0] = c;   // loss_pos
        out[1] = a;   // loss_neg
        out[2] = d;   // count_pos
        out[3] = b;   // count_neg
    }
}

extern "C" void kernel_launch(void* const* d_in, const int* in_sizes, int n_in,
                              void* d_out, int out_size, void* d_ws, size_t ws_size,
                              hipStream_t stream) {
    const float* logit0   = (const float*)d_in[0];
    const float* logit1   = (const float*)d_in[1];
    const float* prob_gt0 = (const float*)d_in[2];
    const float* prob_gt1 = (const float*)d_in[3];
    const int*   coord0   = (const int*)d_in[4];
    const int*   coord1   = (const int*)d_in[5];
    const float* wcls     = (const float*)d_in[6];
    float* out = (float*)d_out;
    float2* ws = (float2*)d_ws;

    mega_kernel<<<TOTAL_WAVES / 4, 256, 0, stream>>>(
        logit0, logit1, prob_gt0, prob_gt1, coord0, coord1, wcls, ws);
    final_reduce<<<1, 1024, 0, stream>>>(ws, out);
}